// Round 5
// baseline (159.651 us; speedup 1.0000x reference)
//
#include <hip/hip_runtime.h>
#include <math.h>

#define NN 4096
#define HH 8
constexpr float SCALE = 0.17677669529663687f;   // 1/sqrt(32)
constexpr float LOG2E = 1.4426950408889634f;
constexpr float SC2   = SCALE * LOG2E;          // folded into Q columns of Wqkv

typedef __bf16 bf16;
typedef __bf16 bf16x8 __attribute__((ext_vector_type(8)));
typedef __bf16 bf16x4 __attribute__((ext_vector_type(4)));
typedef float  f32x4  __attribute__((ext_vector_type(4)));

#define MFMA(a, b, c) __builtin_amdgcn_mfma_f32_16x16x32_bf16((a), (b), (c), 0, 0, 0)

// ---------------------------------------------------------------------------
// W [K][N] fp32 -> W^T hi/lo bf16 [N][K]; optionally scale cols n<256 by SC2.
// ---------------------------------------------------------------------------
template <int K, int N, bool SCALEQ>
__device__ __forceinline__ void wcast_body(const float* __restrict__ W,
                                           bf16* __restrict__ WhT,
                                           bf16* __restrict__ WlT,
                                           int n0, int k0, int t,
                                           float (*tile)[65]) {
#pragma unroll
    for (int p = 0; p < 16; ++p) {
        const int r = p * 4 + (t >> 6);
        const int c = t & 63;
        tile[r][c] = W[(size_t)(k0 + r) * N + n0 + c];
    }
    __syncthreads();
    const int nr = t >> 2, kc0 = (t & 3) * 16;
    const float sc = (SCALEQ && (n0 + nr) < 256) ? SC2 : 1.0f;
    bf16x8 h[2], l[2];
#pragma unroll
    for (int g = 0; g < 2; ++g)
#pragma unroll
        for (int j = 0; j < 8; ++j) {
            const float v = tile[kc0 + g * 8 + j][nr] * sc;
            const bf16 hh = (bf16)v;
            h[g][j] = hh;
            l[g][j] = (bf16)(v - (float)hh);
        }
    const size_t ob = (size_t)(n0 + nr) * K + k0 + kc0;
    *(bf16x8*)&WhT[ob] = h[0];
    *(bf16x8*)&WhT[ob + 8] = h[1];
    *(bf16x8*)&WlT[ob] = l[0];
    *(bf16x8*)&WlT[ob + 8] = l[1];
}

// ---------------------------------------------------------------------------
// Fused preprocessing (block-range dispatch; see round-4 comments).
// ---------------------------------------------------------------------------
__global__ __launch_bounds__(256) void preproc_kernel(
    const float* __restrict__ x, const float* __restrict__ Wqkv,
    const float* __restrict__ Wout, const float* __restrict__ bqkv,
    const float* __restrict__ pe, const float* __restrict__ Wpe,
    const float* __restrict__ bpe,
    bf16* __restrict__ xh, bf16* __restrict__ xl,
    bf16* __restrict__ WqkvhT, bf16* __restrict__ WqkvlT,
    bf16* __restrict__ WouthT, bf16* __restrict__ WoutlT,
    float* __restrict__ bqkv_s, float* __restrict__ ep) {
    __shared__ float tile[64][65];
    const int b = blockIdx.x, t = threadIdx.x;
    if (b < 1024) {
        const int i = (b * 256 + t) * 4;
        const float4 v = *(const float4*)&x[i];
        bf16x4 h, l;
        const float vv[4] = {v.x, v.y, v.z, v.w};
#pragma unroll
        for (int r = 0; r < 4; ++r) {
            h[r] = (bf16)vv[r];
            l[r] = (bf16)(vv[r] - (float)h[r]);
        }
        *(bf16x4*)&xh[i] = h;
        *(bf16x4*)&xl[i] = l;
    } else if (b < 1072) {
        const int bb = b - 1024;
        wcast_body<256, 768, true>(Wqkv, WqkvhT, WqkvlT, (bb % 12) * 64, (bb / 12) * 64, t, tile);
    } else if (b < 1088) {
        const int bb = b - 1072;
        wcast_body<256, 256, false>(Wout, WouthT, WoutlT, (bb % 4) * 64, (bb / 4) * 64, t, tile);
    } else if (b < 1216) {
        const int idx = (b - 1088) * 256 + t;
        const int h = idx >> 12;
        const int n = idx & 4095;
        float acc = bpe[h];
#pragma unroll
        for (int k = 0; k < 16; ++k) acc += pe[n * 16 + k] * Wpe[k * 8 + h];
        ep[h * NN + n] = __builtin_amdgcn_exp2f(-acc * LOG2E - 8.0f);
    } else {
        for (int i = t; i < 768; i += 256)
            bqkv_s[i] = bqkv[i] * (i < 256 ? SC2 : 1.0f);
    }
}

// ---------------------------------------------------------------------------
// 3-term split-bf16 GEMM: C = Ah@Bh^T + Ah@Bl^T + Al@Bh^T + bias.
// MS = m-frags per wave (one B load feeds MS m-tiles -> B traffic / MS).
// ---------------------------------------------------------------------------
template <int NOUT, int MS, typename OT>
__global__ __launch_bounds__(256, 2) void gemm3_kernel(const bf16* __restrict__ Ah,
                                                       const bf16* __restrict__ Al,
                                                       const bf16* __restrict__ BhT,
                                                       const bf16* __restrict__ BlT,
                                                       const float* __restrict__ bias,
                                                       OT* __restrict__ C) {
    const int t = threadIdx.x, wave = t >> 6, lane = t & 63;
    const int quad = lane >> 4, i16 = lane & 15;
    const int m0 = blockIdx.x * (64 * MS) + wave * (16 * MS);
    const int n0 = blockIdx.y * 64;

    bf16x8 ah[MS][8], al[MS][8];
#pragma unroll
    for (int ms = 0; ms < MS; ++ms) {
        const size_t abase = (size_t)(m0 + ms * 16 + i16) * 256 + quad * 8;
#pragma unroll
        for (int kc = 0; kc < 8; ++kc) {
            ah[ms][kc] = *(const bf16x8*)&Ah[abase + kc * 32];
            al[ms][kc] = *(const bf16x8*)&Al[abase + kc * 32];
        }
    }
#pragma unroll
    for (int ns = 0; ns < 4; ++ns) {
        const int n = n0 + ns * 16 + i16;
        const size_t bbase = (size_t)n * 256 + quad * 8;
        f32x4 acc[MS];
#pragma unroll
        for (int ms = 0; ms < MS; ++ms) acc[ms] = f32x4{0.f, 0.f, 0.f, 0.f};
#pragma unroll
        for (int kc = 0; kc < 8; ++kc) {
            const bf16x8 bh = *(const bf16x8*)&BhT[bbase + kc * 32];
            const bf16x8 bl = *(const bf16x8*)&BlT[bbase + kc * 32];
#pragma unroll
            for (int ms = 0; ms < MS; ++ms) {
                acc[ms] = MFMA(ah[ms][kc], bh, acc[ms]);
                acc[ms] = MFMA(ah[ms][kc], bl, acc[ms]);
                acc[ms] = MFMA(al[ms][kc], bh, acc[ms]);
            }
        }
        const float b = bias[n];
#pragma unroll
        for (int ms = 0; ms < MS; ++ms)
#pragma unroll
            for (int r = 0; r < 4; ++r)
                C[(size_t)(m0 + ms * 16 + quad * 4 + r) * NOUT + n] = (OT)(acc[ms][r] + b);
    }
}

// ---------------------------------------------------------------------------
// K and V -> MFMA fragment order; V pre-scaled by ep[key], extended with an
// ep-row so PV-MFMA also produces the softmax denominator l.
// ---------------------------------------------------------------------------
__global__ __launch_bounds__(256) void kvtrans_kernel(const bf16* __restrict__ qkvb,
                                                      const float* __restrict__ ep,
                                                      bf16* __restrict__ Kf,
                                                      bf16* __restrict__ Vf) {
    const int t = threadIdx.x;
    const int kt = blockIdx.y, h = blockIdx.x;
    __shared__ __align__(16) bf16 Ktile[64 * 32];
    __shared__ __align__(16) bf16 Vtile[64 * 32];
    __shared__ float eps[64];
    {
        const int tok = kt * 64 + (t >> 2);
        const int d8 = (t & 3) * 8;
        *(uint4*)&Ktile[(t >> 2) * 32 + d8] =
            *(const uint4*)&qkvb[(size_t)tok * 768 + 256 + h * 32 + d8];
        *(uint4*)&Vtile[(t >> 2) * 32 + d8] =
            *(const uint4*)&qkvb[(size_t)tok * 768 + 512 + h * 32 + d8];
        if (t < 64) eps[t] = ep[h * NN + kt * 64 + t];
    }
    __syncthreads();
    {   // K frags: 4 chunks x 512 bf16 (tile = 4 KB contiguous)
        const int s = t >> 6, l = t & 63, quad = l >> 4, i16 = l & 15;
        bf16x8 o;
#pragma unroll
        for (int j = 0; j < 8; ++j) o[j] = Ktile[(s * 16 + i16) * 32 + quad * 8 + j];
        *(bf16x8*)&Kf[((size_t)(h * 64 + kt) * 4 + s) * 512 + l * 8] = o;
    }
    // V'' frags: 6 chunks x 512 bf16 (3 d-tiles x 2 key-halves; tile = 6 KB)
    for (int c = t; c < 384; c += 256) {
        const int ch = c >> 6, ll = c & 63, qd = ll >> 4, ii = ll & 15;
        const int dt = ch >> 1, kc = ch & 1;
        const int dimp = dt * 16 + ii;
        bf16x8 o;
#pragma unroll
        for (int j = 0; j < 8; ++j) {
            const int key = kc * 32 + qd * 8 + j;
            float v;
            if (dimp < 32)       v = (float)Vtile[key * 32 + dimp] * eps[key];
            else if (dimp == 32) v = eps[key];
            else                 v = 0.f;
            o[j] = (bf16)v;
        }
        *(bf16x8*)&Vf[((size_t)(h * 64 + kt) * 6 + ch) * 512 + ll * 8] = o;
    }
}

// ---------------------------------------------------------------------------
// Fixed-m flash attention, LDS-shared double-buffered K/V tiles.
// grid (h, qb), block = 4 waves; wave w owns queries qb*64+w*16..+15 and
// walks ALL 64 key tiles. One __syncthreads per iter; K/V frag reads from
// LDS are shared by all 4 waves (4x less L2 traffic than per-wave loads).
// ---------------------------------------------------------------------------
__global__ __launch_bounds__(256, 2) void attn_kernel(const bf16* __restrict__ qkvb,
                                                      const bf16* __restrict__ Kf,
                                                      const bf16* __restrict__ Vf,
                                                      bf16* __restrict__ aoh,
                                                      bf16* __restrict__ aol) {
    const int t = threadIdx.x, wave = t >> 6, lane = t & 63;
    const int quad = lane >> 4, i16 = lane & 15;
    const int qb = blockIdx.y, h = blockIdx.x;

    __shared__ __align__(16) bf16 Kbuf[2][2048];    // 4 KB tiles
    __shared__ __align__(16) bf16 Vbuf[2][3072];    // 6 KB tiles
    __shared__ __align__(16) bf16 Pt[4][16 * 72];   // per-wave P^T

    const int q0 = qb * 64 + wave * 16;
    const bf16x8 qf = *(const bf16x8*)&qkvb[(size_t)(q0 + i16) * 768 + h * 32 + quad * 8];

    f32x4 o[3];
#pragma unroll
    for (int dt = 0; dt < 3; ++dt) o[dt] = f32x4{0.f, 0.f, 0.f, 0.f};

    const bf16* kbase = Kf + (size_t)(h * 64) * 2048;
    const bf16* vbase = Vf + (size_t)(h * 64) * 3072;
    bf16* ptw = &Pt[wave][0];
    const int t2 = t - 128;

    // prologue: stage tile 0 into buf 0
    {
        const uint4 kr = *(const uint4*)&kbase[t * 8];
        const uint4 vr = *(const uint4*)&vbase[t * 8];
        *(uint4*)&Kbuf[0][t * 8] = kr;
        *(uint4*)&Vbuf[0][t * 8] = vr;
        if (t2 >= 0) {
            const uint4 vr2 = *(const uint4*)&vbase[2048 + t2 * 8];
            *(uint4*)&Vbuf[0][2048 + t2 * 8] = vr2;
        }
    }
    __syncthreads();

    for (int it = 0; it < 64; ++it) {
        const int buf = it & 1;
        const int nt = (it < 63) ? it + 1 : it;
        // issue next-tile global loads early (hide L2 latency under compute)
        const uint4 kst = *(const uint4*)&kbase[(size_t)nt * 2048 + t * 8];
        const uint4 vst = *(const uint4*)&vbase[(size_t)nt * 3072 + t * 8];
        uint4 vst2;
        if (t2 >= 0) vst2 = *(const uint4*)&vbase[(size_t)nt * 3072 + 2048 + t2 * 8];

        // ---- QK^T: 4 chunks of 16 keys (S^T: row=key, col=query) ----
        const f32x4 z = {0.f, 0.f, 0.f, 0.f};
        f32x4 sf[4];
#pragma unroll
        for (int ks = 0; ks < 4; ++ks) {
            const bf16x8 ka = *(const bf16x8*)&Kbuf[buf][ks * 512 + lane * 8];
            sf[ks] = MFMA(ka, qf, z);
        }

        // ---- P = exp2(s) -> wave-private LDS ----
#pragma unroll
        for (int ks = 0; ks < 4; ++ks) {
            bf16x4 pk;
#pragma unroll
            for (int r = 0; r < 4; ++r)
                pk[r] = (bf16)__builtin_amdgcn_exp2f(sf[ks][r]);
            *(bf16x4*)&ptw[i16 * 72 + ks * 16 + quad * 4] = pk;
        }
        asm volatile("s_waitcnt lgkmcnt(0)" ::: "memory");

        // ---- PV: O^T += V''_frag x P^T (o[2] row0 accumulates l) ----
        {
            const bf16x8 pb0 = *(const bf16x8*)&ptw[i16 * 72 + 0 * 32 + quad * 8];
            const bf16x8 pb1 = *(const bf16x8*)&ptw[i16 * 72 + 1 * 32 + quad * 8];
#pragma unroll
            for (int dt = 0; dt < 3; ++dt) {
                const bf16x8 va0 = *(const bf16x8*)&Vbuf[buf][(dt * 2 + 0) * 512 + lane * 8];
                const bf16x8 va1 = *(const bf16x8*)&Vbuf[buf][(dt * 2 + 1) * 512 + lane * 8];
                o[dt] = MFMA(va0, pb0, o[dt]);
                o[dt] = MFMA(va1, pb1, o[dt]);
            }
        }

        // ---- commit staged tile to the other buffer, sync ----
        *(uint4*)&Kbuf[buf ^ 1][t * 8] = kst;
        *(uint4*)&Vbuf[buf ^ 1][t * 8] = vst;
        if (t2 >= 0) *(uint4*)&Vbuf[buf ^ 1][2048 + t2 * 8] = vst2;
        __syncthreads();
    }

    // l for query i16 lives in o[2] reg 0 of lanes 0..15 (dim'=32 row)
    const float linv = 1.0f / __shfl(o[2][0], i16, 64);
    const int row = q0 + i16;
#pragma unroll
    for (int dt = 0; dt < 2; ++dt) {
        bf16x4 hi, lo;
#pragma unroll
        for (int r = 0; r < 4; ++r) {
            const float v = o[dt][r] * linv;
            hi[r] = (bf16)v;
            lo[r] = (bf16)(v - (float)hi[r]);
        }
        const size_t ob = (size_t)row * 256 + h * 32 + dt * 16 + quad * 4;
        *(bf16x4*)&aoh[ob] = hi;
        *(bf16x4*)&aol[ob] = lo;
    }
}

// ---------------------------------------------------------------------------
extern "C" void kernel_launch(void* const* d_in, const int* in_sizes, int n_in,
                              void* d_out, int out_size, void* d_ws, size_t ws_size,
                              hipStream_t stream) {
    const float* x    = (const float*)d_in[0];
    const float* pe   = (const float*)d_in[1];
    const float* Wqkv = (const float*)d_in[2];
    const float* bqkv = (const float*)d_in[3];
    const float* Wpe  = (const float*)d_in[4];
    const float* bpe  = (const float*)d_in[5];
    const float* Wout = (const float*)d_in[6];
    const float* bout = (const float*)d_in[7];
    float* out = (float*)d_out;

    char* ws = (char*)d_ws;
    bf16*  xh      = (bf16*)(ws);                   // 2 MB
    bf16*  xl      = (bf16*)(ws + 2097152);         // 2 MB
    bf16*  WqkvhT  = (bf16*)(ws + 4194304);         // 384 KB
    bf16*  WqkvlT  = (bf16*)(ws + 4587520);         // 384 KB
    bf16*  WouthT  = (bf16*)(ws + 4980736);         // 128 KB
    bf16*  WoutlT  = (bf16*)(ws + 5111808);         // 128 KB
    float* bqkv_s  = (float*)(ws + 5242880);        // 3 KB
    bf16*  qkvb    = (bf16*)(ws + 5245952);         // 6 MB
    float* ep      = (float*)(ws + 11537408);       // 128 KB
    bf16*  Kf      = (bf16*)(ws + 11668480);        // 2 MB
    bf16*  Vf      = (bf16*)(ws + 13765632);        // 3 MB
    bf16*  aoh     = (bf16*)(ws + 16911360);        // 2 MB
    bf16*  aol     = (bf16*)(ws + 19008512);        // 2 MB -> 21.1 MB total

    preproc_kernel<<<1217, 256, 0, stream>>>(x, Wqkv, Wout, bqkv, pe, Wpe, bpe,
                                             xh, xl, WqkvhT, WqkvlT, WouthT, WoutlT,
                                             bqkv_s, ep);
    gemm3_kernel<768, 2, bf16><<<dim3(32, 12), 256, 0, stream>>>(xh, xl, WqkvhT, WqkvlT, bqkv_s, qkvb);
    kvtrans_kernel<<<dim3(HH, 64), 256, 0, stream>>>(qkvb, ep, Kf, Vf);
    attn_kernel<<<dim3(HH, NN / 64), 256, 0, stream>>>(qkvb, Kf, Vf, aoh, aol);
    gemm3_kernel<256, 1, float><<<dim3(64, 4), 256, 0, stream>>>(aoh, aol, WouthT, WoutlT, bout, out);
}

// Round 6
// 132.939 us; speedup vs baseline: 1.2009x; 1.2009x over previous
//
#include <hip/hip_runtime.h>
#include <math.h>

#define NN 4096
#define HH 8
constexpr float SCALE = 0.17677669529663687f;   // 1/sqrt(32)
constexpr float LOG2E = 1.4426950408889634f;
constexpr float SC2   = SCALE * LOG2E;          // folded into Q columns of Wqkv

typedef __bf16 bf16;
typedef __bf16 bf16x8 __attribute__((ext_vector_type(8)));
typedef __bf16 bf16x4 __attribute__((ext_vector_type(4)));
typedef float  f32x4  __attribute__((ext_vector_type(4)));

#define MFMA(a, b, c) __builtin_amdgcn_mfma_f32_16x16x32_bf16((a), (b), (c), 0, 0, 0)

// ---------------------------------------------------------------------------
// W [K][N] fp32 -> W^T hi/lo bf16 [N][K]; optionally scale cols n<256 by SC2.
// ---------------------------------------------------------------------------
template <int K, int N, bool SCALEQ>
__device__ __forceinline__ void wcast_body(const float* __restrict__ W,
                                           bf16* __restrict__ WhT,
                                           bf16* __restrict__ WlT,
                                           int n0, int k0, int t,
                                           float (*tile)[65]) {
#pragma unroll
    for (int p = 0; p < 16; ++p) {
        const int r = p * 4 + (t >> 6);
        const int c = t & 63;
        tile[r][c] = W[(size_t)(k0 + r) * N + n0 + c];
    }
    __syncthreads();
    const int nr = t >> 2, kc0 = (t & 3) * 16;
    const float sc = (SCALEQ && (n0 + nr) < 256) ? SC2 : 1.0f;
    bf16x8 h[2], l[2];
#pragma unroll
    for (int g = 0; g < 2; ++g)
#pragma unroll
        for (int j = 0; j < 8; ++j) {
            const float v = tile[kc0 + g * 8 + j][nr] * sc;
            const bf16 hh = (bf16)v;
            h[g][j] = hh;
            l[g][j] = (bf16)(v - (float)hh);
        }
    const size_t ob = (size_t)(n0 + nr) * K + k0 + kc0;
    *(bf16x8*)&WhT[ob] = h[0];
    *(bf16x8*)&WhT[ob + 8] = h[1];
    *(bf16x8*)&WlT[ob] = l[0];
    *(bf16x8*)&WlT[ob + 8] = l[1];
}

// ---------------------------------------------------------------------------
// Fused preprocessing (block-range dispatch; see round-4 comments).
// ---------------------------------------------------------------------------
__global__ __launch_bounds__(256) void preproc_kernel(
    const float* __restrict__ x, const float* __restrict__ Wqkv,
    const float* __restrict__ Wout, const float* __restrict__ bqkv,
    const float* __restrict__ pe, const float* __restrict__ Wpe,
    const float* __restrict__ bpe,
    bf16* __restrict__ xh, bf16* __restrict__ xl,
    bf16* __restrict__ WqkvhT, bf16* __restrict__ WqkvlT,
    bf16* __restrict__ WouthT, bf16* __restrict__ WoutlT,
    float* __restrict__ bqkv_s, float* __restrict__ ep) {
    __shared__ float tile[64][65];
    const int b = blockIdx.x, t = threadIdx.x;
    if (b < 1024) {
        const int i = (b * 256 + t) * 4;
        const float4 v = *(const float4*)&x[i];
        bf16x4 h, l;
        const float vv[4] = {v.x, v.y, v.z, v.w};
#pragma unroll
        for (int r = 0; r < 4; ++r) {
            h[r] = (bf16)vv[r];
            l[r] = (bf16)(vv[r] - (float)h[r]);
        }
        *(bf16x4*)&xh[i] = h;
        *(bf16x4*)&xl[i] = l;
    } else if (b < 1072) {
        const int bb = b - 1024;
        wcast_body<256, 768, true>(Wqkv, WqkvhT, WqkvlT, (bb % 12) * 64, (bb / 12) * 64, t, tile);
    } else if (b < 1088) {
        const int bb = b - 1072;
        wcast_body<256, 256, false>(Wout, WouthT, WoutlT, (bb % 4) * 64, (bb / 4) * 64, t, tile);
    } else if (b < 1216) {
        const int idx = (b - 1088) * 256 + t;
        const int h = idx >> 12;
        const int n = idx & 4095;
        float acc = bpe[h];
#pragma unroll
        for (int k = 0; k < 16; ++k) acc += pe[n * 16 + k] * Wpe[k * 8 + h];
        ep[h * NN + n] = __builtin_amdgcn_exp2f(-acc * LOG2E - 8.0f);
    } else {
        for (int i = t; i < 768; i += 256)
            bqkv_s[i] = bqkv[i] * (i < 256 ? SC2 : 1.0f);
    }
}

// ---------------------------------------------------------------------------
// Staged 3-term split-bf16 GEMM: C = Ah@Bh^T + Ah@Bl^T + Al@Bh^T + bias.
// C-tile 128(M) x NTILE(N); the full B panel (hi+lo, K=256) is staged ONCE
// into LDS in MFMA-fragment order (reads are lane*16B contiguous -> conflict
// free), shared by all 4 waves. One barrier total; then pure LDS->MFMA.
// Grid (32, NOUT/NTILE); NTILE in {16,48} keeps grid = 512 = 2 blocks/CU.
// ---------------------------------------------------------------------------
template <int NOUT, int NTILE, typename OT>
__global__ __launch_bounds__(256, 2) void gemm3s_kernel(const bf16* __restrict__ Ah,
                                                        const bf16* __restrict__ Al,
                                                        const bf16* __restrict__ BhT,
                                                        const bf16* __restrict__ BlT,
                                                        const float* __restrict__ bias,
                                                        OT* __restrict__ C) {
    constexpr int NS = NTILE / 16;
    const int t = threadIdx.x, wave = t >> 6, lane = t & 63;
    const int quad = lane >> 4, i16 = lane & 15;
    const int m0 = blockIdx.x * 128 + wave * 32;
    const int n0 = blockIdx.y * NTILE;

    __shared__ __align__(16) bf16 Bs[NTILE * 512]; // hi: [0,NS*8) chunks, lo after

    {   // stage B panel in fragment order: chunk c -> 64 lanes x 16 B
        const int l = t & 63, i16l = l & 15, ql = l >> 4;
#pragma unroll
        for (int c = t >> 6; c < NS * 16; c += 4) {
            const bool lo = c >= NS * 8;
            const int cc = lo ? c - NS * 8 : c;
            const int nsi = cc >> 3, kc = cc & 7;
            const bf16* src = (lo ? BlT : BhT) +
                (size_t)(n0 + nsi * 16 + i16l) * 256 + kc * 32 + ql * 8;
            *(uint4*)&Bs[c * 512 + l * 8] = *(const uint4*)src;
        }
    }

    // A fragments (wave-private rows, from global/L2)
    bf16x8 ah[2][8], al[2][8];
#pragma unroll
    for (int ms = 0; ms < 2; ++ms) {
        const size_t abase = (size_t)(m0 + ms * 16 + i16) * 256 + quad * 8;
#pragma unroll
        for (int kc = 0; kc < 8; ++kc) {
            ah[ms][kc] = *(const bf16x8*)&Ah[abase + kc * 32];
            al[ms][kc] = *(const bf16x8*)&Al[abase + kc * 32];
        }
    }
    __syncthreads();

#pragma unroll
    for (int nsi = 0; nsi < NS; ++nsi) {
        f32x4 acc[2];
        acc[0] = f32x4{0.f, 0.f, 0.f, 0.f};
        acc[1] = f32x4{0.f, 0.f, 0.f, 0.f};
#pragma unroll
        for (int kc = 0; kc < 8; ++kc) {
            const bf16x8 bh = *(const bf16x8*)&Bs[(nsi * 8 + kc) * 512 + lane * 8];
            const bf16x8 bl = *(const bf16x8*)&Bs[((NS + nsi) * 8 + kc) * 512 + lane * 8];
            acc[0] = MFMA(ah[0][kc], bh, acc[0]);
            acc[0] = MFMA(ah[0][kc], bl, acc[0]);
            acc[0] = MFMA(al[0][kc], bh, acc[0]);
            acc[1] = MFMA(ah[1][kc], bh, acc[1]);
            acc[1] = MFMA(ah[1][kc], bl, acc[1]);
            acc[1] = MFMA(al[1][kc], bh, acc[1]);
        }
        const int n = n0 + nsi * 16 + i16;
        const float b = bias[n];
#pragma unroll
        for (int ms = 0; ms < 2; ++ms)
#pragma unroll
            for (int r = 0; r < 4; ++r)
                C[(size_t)(m0 + ms * 16 + quad * 4 + r) * NOUT + n] = (OT)(acc[ms][r] + b);
    }
}

// ---------------------------------------------------------------------------
// K and V -> MFMA fragment order; V pre-scaled by ep[key], extended with an
// ep-row so PV-MFMA also produces the softmax denominator l.
// ---------------------------------------------------------------------------
__global__ __launch_bounds__(256) void kvtrans_kernel(const bf16* __restrict__ qkvb,
                                                      const float* __restrict__ ep,
                                                      bf16* __restrict__ Kf,
                                                      bf16* __restrict__ Vf) {
    const int t = threadIdx.x;
    const int kt = blockIdx.y, h = blockIdx.x;
    __shared__ __align__(16) bf16 Ktile[64 * 32];
    __shared__ __align__(16) bf16 Vtile[64 * 32];
    __shared__ float eps[64];
    {
        const int tok = kt * 64 + (t >> 2);
        const int d8 = (t & 3) * 8;
        *(uint4*)&Ktile[(t >> 2) * 32 + d8] =
            *(const uint4*)&qkvb[(size_t)tok * 768 + 256 + h * 32 + d8];
        *(uint4*)&Vtile[(t >> 2) * 32 + d8] =
            *(const uint4*)&qkvb[(size_t)tok * 768 + 512 + h * 32 + d8];
        if (t < 64) eps[t] = ep[h * NN + kt * 64 + t];
    }
    __syncthreads();
    {   // K frags: 4 chunks x 512 bf16 (tile = 4 KB contiguous)
        const int s = t >> 6, l = t & 63, quad = l >> 4, i16 = l & 15;
        bf16x8 o;
#pragma unroll
        for (int j = 0; j < 8; ++j) o[j] = Ktile[(s * 16 + i16) * 32 + quad * 8 + j];
        *(bf16x8*)&Kf[((size_t)(h * 64 + kt) * 4 + s) * 512 + l * 8] = o;
    }
    // V'' frags: 6 chunks x 512 bf16 (3 d-tiles x 2 key-halves; tile = 6 KB)
    for (int c = t; c < 384; c += 256) {
        const int ch = c >> 6, ll = c & 63, qd = ll >> 4, ii = ll & 15;
        const int dt = ch >> 1, kc = ch & 1;
        const int dimp = dt * 16 + ii;
        bf16x8 o;
#pragma unroll
        for (int j = 0; j < 8; ++j) {
            const int key = kc * 32 + qd * 8 + j;
            float v;
            if (dimp < 32)       v = (float)Vtile[key * 32 + dimp] * eps[key];
            else if (dimp == 32) v = eps[key];
            else                 v = 0.f;
            o[j] = (bf16)v;
        }
        *(bf16x8*)&Vf[((size_t)(h * 64 + kt) * 6 + ch) * 512 + ll * 8] = o;
    }
}

// ---------------------------------------------------------------------------
// Fixed-m flash attention (round-4 version: no barriers in main loop, K/V
// frags direct global->register, kh-split). grid (h, qb).
// ---------------------------------------------------------------------------
__global__ __launch_bounds__(256, 2) void attn_kernel(const bf16* __restrict__ qkvb,
                                                      const bf16* __restrict__ Kf,
                                                      const bf16* __restrict__ Vf,
                                                      bf16* __restrict__ aoh,
                                                      bf16* __restrict__ aol) {
    const int t = threadIdx.x, wave = t >> 6, lane = t & 63;
    const int quad = lane >> 4, i16 = lane & 15;
    const int qb = blockIdx.y, h = blockIdx.x;
    const int qg = wave & 1, kh = wave >> 1;

    __shared__ __align__(16) bf16 Pt[4][2][16 * 72]; // per-wave P^T, bank-even
    __shared__ __align__(16) float Mrg[2][64][24];   // key-half merge

    const int q0 = qb * 64 + qg * 32;
    const bf16x8 qf0 = *(const bf16x8*)&qkvb[(size_t)(q0 + i16) * 768 + h * 32 + quad * 8];
    const bf16x8 qf1 = *(const bf16x8*)&qkvb[(size_t)(q0 + 16 + i16) * 768 + h * 32 + quad * 8];

    f32x4 o[3][2];
#pragma unroll
    for (int dt = 0; dt < 3; ++dt)
#pragma unroll
        for (int qs = 0; qs < 2; ++qs) o[dt][qs] = f32x4{0.f, 0.f, 0.f, 0.f};

    const bf16* kb = Kf + (size_t)(h * 64) * 2048 + lane * 8;
    const bf16* vb = Vf + (size_t)(h * 64) * 3072 + lane * 8;
    bf16* ptw = &Pt[wave][0][0];

    const int kt0 = kh * 32;
    bf16x8 kcur[4];
#pragma unroll
    for (int s = 0; s < 4; ++s)
        kcur[s] = *(const bf16x8*)&kb[((size_t)kt0 * 4 + s) * 512];

    for (int it = 0; it < 32; ++it) {
        const int kt = kt0 + it;
        bf16x8 vv[6];
#pragma unroll
        for (int c = 0; c < 6; ++c)
            vv[c] = *(const bf16x8*)&vb[((size_t)kt * 6 + c) * 512];
        bf16x8 knx[4];
        if (it < 31) {
#pragma unroll
            for (int s = 0; s < 4; ++s)
                knx[s] = *(const bf16x8*)&kb[((size_t)(kt + 1) * 4 + s) * 512];
        } else {
#pragma unroll
            for (int s = 0; s < 4; ++s) knx[s] = kcur[s];
        }

        const f32x4 z = {0.f, 0.f, 0.f, 0.f};
        f32x4 sf[4][2];
#pragma unroll
        for (int ks = 0; ks < 4; ++ks) {
            sf[ks][0] = MFMA(kcur[ks], qf0, z);
            sf[ks][1] = MFMA(kcur[ks], qf1, z);
        }

#pragma unroll
        for (int qs = 0; qs < 2; ++qs)
#pragma unroll
            for (int ks = 0; ks < 4; ++ks) {
                bf16x4 pk;
#pragma unroll
                for (int r = 0; r < 4; ++r)
                    pk[r] = (bf16)__builtin_amdgcn_exp2f(sf[ks][qs][r]);
                *(bf16x4*)&ptw[qs * (16 * 72) + i16 * 72 + ks * 16 + quad * 4] = pk;
            }
        asm volatile("s_waitcnt lgkmcnt(0)" ::: "memory");

#pragma unroll
        for (int qs = 0; qs < 2; ++qs) {
            const bf16x8 pb0 = *(const bf16x8*)&ptw[qs * (16 * 72) + i16 * 72 + 0 * 32 + quad * 8];
            const bf16x8 pb1 = *(const bf16x8*)&ptw[qs * (16 * 72) + i16 * 72 + 1 * 32 + quad * 8];
#pragma unroll
            for (int dt = 0; dt < 3; ++dt) {
                o[dt][qs] = MFMA(vv[dt * 2 + 0], pb0, o[dt][qs]);
                o[dt][qs] = MFMA(vv[dt * 2 + 1], pb1, o[dt][qs]);
            }
        }
#pragma unroll
        for (int s = 0; s < 4; ++s) kcur[s] = knx[s];
    }

    if (kh == 1) {
#pragma unroll
        for (int dt = 0; dt < 3; ++dt)
#pragma unroll
            for (int qs = 0; qs < 2; ++qs)
                *(f32x4*)&Mrg[qg][lane][(dt * 2 + qs) * 4] = o[dt][qs];
    }
    __syncthreads();
    if (kh == 0) {
#pragma unroll
        for (int dt = 0; dt < 3; ++dt)
#pragma unroll
            for (int qs = 0; qs < 2; ++qs)
                o[dt][qs] += *(const f32x4*)&Mrg[qg][lane][(dt * 2 + qs) * 4];
        const float linv0 = 1.0f / __shfl(o[2][0][0], i16, 64);
        const float linv1 = 1.0f / __shfl(o[2][1][0], i16, 64);
#pragma unroll
        for (int qs = 0; qs < 2; ++qs) {
            const float inv = qs ? linv1 : linv0;
            const int row = q0 + qs * 16 + i16;
#pragma unroll
            for (int dt = 0; dt < 2; ++dt) {
                bf16x4 hi, lo;
#pragma unroll
                for (int r = 0; r < 4; ++r) {
                    const float v = o[dt][qs][r] * inv;
                    hi[r] = (bf16)v;
                    lo[r] = (bf16)(v - (float)hi[r]);
                }
                const size_t ob = (size_t)row * 256 + h * 32 + dt * 16 + quad * 4;
                *(bf16x4*)&aoh[ob] = hi;
                *(bf16x4*)&aol[ob] = lo;
            }
        }
    }
}

// ---------------------------------------------------------------------------
extern "C" void kernel_launch(void* const* d_in, const int* in_sizes, int n_in,
                              void* d_out, int out_size, void* d_ws, size_t ws_size,
                              hipStream_t stream) {
    const float* x    = (const float*)d_in[0];
    const float* pe   = (const float*)d_in[1];
    const float* Wqkv = (const float*)d_in[2];
    const float* bqkv = (const float*)d_in[3];
    const float* Wpe  = (const float*)d_in[4];
    const float* bpe  = (const float*)d_in[5];
    const float* Wout = (const float*)d_in[6];
    const float* bout = (const float*)d_in[7];
    float* out = (float*)d_out;

    char* ws = (char*)d_ws;
    bf16*  xh      = (bf16*)(ws);                   // 2 MB
    bf16*  xl      = (bf16*)(ws + 2097152);         // 2 MB
    bf16*  WqkvhT  = (bf16*)(ws + 4194304);         // 384 KB
    bf16*  WqkvlT  = (bf16*)(ws + 4587520);         // 384 KB
    bf16*  WouthT  = (bf16*)(ws + 4980736);         // 128 KB
    bf16*  WoutlT  = (bf16*)(ws + 5111808);         // 128 KB
    float* bqkv_s  = (float*)(ws + 5242880);        // 3 KB
    bf16*  qkvb    = (bf16*)(ws + 5245952);         // 6 MB
    float* ep      = (float*)(ws + 11537408);       // 128 KB
    bf16*  Kf      = (bf16*)(ws + 11668480);        // 2 MB
    bf16*  Vf      = (bf16*)(ws + 13765632);        // 3 MB
    bf16*  aoh     = (bf16*)(ws + 16911360);        // 2 MB
    bf16*  aol     = (bf16*)(ws + 19008512);        // 2 MB -> 21.1 MB total

    preproc_kernel<<<1217, 256, 0, stream>>>(x, Wqkv, Wout, bqkv, pe, Wpe, bpe,
                                             xh, xl, WqkvhT, WqkvlT, WouthT, WoutlT,
                                             bqkv_s, ep);
    gemm3s_kernel<768, 48, bf16><<<dim3(32, 16), 256, 0, stream>>>(xh, xl, WqkvhT, WqkvlT, bqkv_s, qkvb);
    kvtrans_kernel<<<dim3(HH, 64), 256, 0, stream>>>(qkvb, ep, Kf, Vf);
    attn_kernel<<<dim3(HH, NN / 64), 256, 0, stream>>>(qkvb, Kf, Vf, aoh, aol);
    gemm3s_kernel<256, 16, float><<<dim3(32, 16), 256, 0, stream>>>(aoh, aol, WouthT, WoutlT, bout, out);
}

// Round 7
// 130.267 us; speedup vs baseline: 1.2256x; 1.0205x over previous
//
#include <hip/hip_runtime.h>
#include <math.h>

#define NN 4096
#define HH 8
constexpr float SCALE = 0.17677669529663687f;   // 1/sqrt(32)
constexpr float LOG2E = 1.4426950408889634f;
constexpr float SC2   = SCALE * LOG2E;          // folded into Q columns of Wqkv

typedef __bf16 bf16;
typedef __bf16 bf16x8 __attribute__((ext_vector_type(8)));
typedef __bf16 bf16x4 __attribute__((ext_vector_type(4)));
typedef float  f32x4  __attribute__((ext_vector_type(4)));

#define MFMA(a, b, c) __builtin_amdgcn_mfma_f32_16x16x32_bf16((a), (b), (c), 0, 0, 0)

// ---------------------------------------------------------------------------
// W [K][N] fp32 -> W^T hi/lo bf16 [N][K]; optionally scale cols n<256 by SC2.
// ---------------------------------------------------------------------------
template <int K, int N, bool SCALEQ>
__device__ __forceinline__ void wcast_body(const float* __restrict__ W,
                                           bf16* __restrict__ WhT,
                                           bf16* __restrict__ WlT,
                                           int n0, int k0, int t,
                                           float (*tile)[65]) {
#pragma unroll
    for (int p = 0; p < 16; ++p) {
        const int r = p * 4 + (t >> 6);
        const int c = t & 63;
        tile[r][c] = W[(size_t)(k0 + r) * N + n0 + c];
    }
    __syncthreads();
    const int nr = t >> 2, kc0 = (t & 3) * 16;
    const float sc = (SCALEQ && (n0 + nr) < 256) ? SC2 : 1.0f;
    bf16x8 h[2], l[2];
#pragma unroll
    for (int g = 0; g < 2; ++g)
#pragma unroll
        for (int j = 0; j < 8; ++j) {
            const float v = tile[kc0 + g * 8 + j][nr] * sc;
            const bf16 hh = (bf16)v;
            h[g][j] = hh;
            l[g][j] = (bf16)(v - (float)hh);
        }
    const size_t ob = (size_t)(n0 + nr) * K + k0 + kc0;
    *(bf16x8*)&WhT[ob] = h[0];
    *(bf16x8*)&WhT[ob + 8] = h[1];
    *(bf16x8*)&WlT[ob] = l[0];
    *(bf16x8*)&WlT[ob + 8] = l[1];
}

// ---------------------------------------------------------------------------
// Fused preprocessing (block-range dispatch; see round-4 comments).
// ---------------------------------------------------------------------------
__global__ __launch_bounds__(256) void preproc_kernel(
    const float* __restrict__ x, const float* __restrict__ Wqkv,
    const float* __restrict__ Wout, const float* __restrict__ bqkv,
    const float* __restrict__ pe, const float* __restrict__ Wpe,
    const float* __restrict__ bpe,
    bf16* __restrict__ xh, bf16* __restrict__ xl,
    bf16* __restrict__ WqkvhT, bf16* __restrict__ WqkvlT,
    bf16* __restrict__ WouthT, bf16* __restrict__ WoutlT,
    float* __restrict__ bqkv_s, float* __restrict__ ep) {
    __shared__ float tile[64][65];
    const int b = blockIdx.x, t = threadIdx.x;
    if (b < 1024) {
        const int i = (b * 256 + t) * 4;
        const float4 v = *(const float4*)&x[i];
        bf16x4 h, l;
        const float vv[4] = {v.x, v.y, v.z, v.w};
#pragma unroll
        for (int r = 0; r < 4; ++r) {
            h[r] = (bf16)vv[r];
            l[r] = (bf16)(vv[r] - (float)h[r]);
        }
        *(bf16x4*)&xh[i] = h;
        *(bf16x4*)&xl[i] = l;
    } else if (b < 1072) {
        const int bb = b - 1024;
        wcast_body<256, 768, true>(Wqkv, WqkvhT, WqkvlT, (bb % 12) * 64, (bb / 12) * 64, t, tile);
    } else if (b < 1088) {
        const int bb = b - 1072;
        wcast_body<256, 256, false>(Wout, WouthT, WoutlT, (bb % 4) * 64, (bb / 4) * 64, t, tile);
    } else if (b < 1216) {
        const int idx = (b - 1088) * 256 + t;
        const int h = idx >> 12;
        const int n = idx & 4095;
        float acc = bpe[h];
#pragma unroll
        for (int k = 0; k < 16; ++k) acc += pe[n * 16 + k] * Wpe[k * 8 + h];
        ep[h * NN + n] = __builtin_amdgcn_exp2f(-acc * LOG2E - 8.0f);
    } else {
        for (int i = t; i < 768; i += 256)
            bqkv_s[i] = bqkv[i] * (i < 256 ? SC2 : 1.0f);
    }
}

// ---------------------------------------------------------------------------
// Staged 3-term split-bf16 GEMM (round-6, proven): B panel staged once in LDS
// fragment order, shared by 4 waves; one barrier; pure LDS->MFMA after.
// ---------------------------------------------------------------------------
template <int NOUT, int NTILE, typename OT>
__global__ __launch_bounds__(256, 2) void gemm3s_kernel(const bf16* __restrict__ Ah,
                                                        const bf16* __restrict__ Al,
                                                        const bf16* __restrict__ BhT,
                                                        const bf16* __restrict__ BlT,
                                                        const float* __restrict__ bias,
                                                        OT* __restrict__ C) {
    constexpr int NS = NTILE / 16;
    const int t = threadIdx.x, wave = t >> 6, lane = t & 63;
    const int quad = lane >> 4, i16 = lane & 15;
    const int m0 = blockIdx.x * 128 + wave * 32;
    const int n0 = blockIdx.y * NTILE;

    __shared__ __align__(16) bf16 Bs[NTILE * 512]; // hi: [0,NS*8) chunks, lo after

    {   // stage B panel in fragment order: chunk c -> 64 lanes x 16 B
        const int l = t & 63, i16l = l & 15, ql = l >> 4;
#pragma unroll
        for (int c = t >> 6; c < NS * 16; c += 4) {
            const bool lo = c >= NS * 8;
            const int cc = lo ? c - NS * 8 : c;
            const int nsi = cc >> 3, kc = cc & 7;
            const bf16* src = (lo ? BlT : BhT) +
                (size_t)(n0 + nsi * 16 + i16l) * 256 + kc * 32 + ql * 8;
            *(uint4*)&Bs[c * 512 + l * 8] = *(const uint4*)src;
        }
    }

    bf16x8 ah[2][8], al[2][8];
#pragma unroll
    for (int ms = 0; ms < 2; ++ms) {
        const size_t abase = (size_t)(m0 + ms * 16 + i16) * 256 + quad * 8;
#pragma unroll
        for (int kc = 0; kc < 8; ++kc) {
            ah[ms][kc] = *(const bf16x8*)&Ah[abase + kc * 32];
            al[ms][kc] = *(const bf16x8*)&Al[abase + kc * 32];
        }
    }
    __syncthreads();

#pragma unroll
    for (int nsi = 0; nsi < NS; ++nsi) {
        f32x4 acc[2];
        acc[0] = f32x4{0.f, 0.f, 0.f, 0.f};
        acc[1] = f32x4{0.f, 0.f, 0.f, 0.f};
#pragma unroll
        for (int kc = 0; kc < 8; ++kc) {
            const bf16x8 bh = *(const bf16x8*)&Bs[(nsi * 8 + kc) * 512 + lane * 8];
            const bf16x8 bl = *(const bf16x8*)&Bs[((NS + nsi) * 8 + kc) * 512 + lane * 8];
            acc[0] = MFMA(ah[0][kc], bh, acc[0]);
            acc[0] = MFMA(ah[0][kc], bl, acc[0]);
            acc[0] = MFMA(al[0][kc], bh, acc[0]);
            acc[1] = MFMA(ah[1][kc], bh, acc[1]);
            acc[1] = MFMA(ah[1][kc], bl, acc[1]);
            acc[1] = MFMA(al[1][kc], bh, acc[1]);
        }
        const int n = n0 + nsi * 16 + i16;
        const float b = bias[n];
#pragma unroll
        for (int ms = 0; ms < 2; ++ms)
#pragma unroll
            for (int r = 0; r < 4; ++r)
                C[(size_t)(m0 + ms * 16 + quad * 4 + r) * NOUT + n] = (OT)(acc[ms][r] + b);
    }
}

// ---------------------------------------------------------------------------
// K and V -> MFMA fragment order; V pre-scaled by ep[key], extended with an
// ep-row so PV-MFMA also produces the softmax denominator l.
// ---------------------------------------------------------------------------
__global__ __launch_bounds__(256) void kvtrans_kernel(const bf16* __restrict__ qkvb,
                                                      const float* __restrict__ ep,
                                                      bf16* __restrict__ Kf,
                                                      bf16* __restrict__ Vf) {
    const int t = threadIdx.x;
    const int kt = blockIdx.y, h = blockIdx.x;
    __shared__ __align__(16) bf16 Ktile[64 * 32];
    __shared__ __align__(16) bf16 Vtile[64 * 32];
    __shared__ float eps[64];
    {
        const int tok = kt * 64 + (t >> 2);
        const int d8 = (t & 3) * 8;
        *(uint4*)&Ktile[(t >> 2) * 32 + d8] =
            *(const uint4*)&qkvb[(size_t)tok * 768 + 256 + h * 32 + d8];
        *(uint4*)&Vtile[(t >> 2) * 32 + d8] =
            *(const uint4*)&qkvb[(size_t)tok * 768 + 512 + h * 32 + d8];
        if (t < 64) eps[t] = ep[h * NN + kt * 64 + t];
    }
    __syncthreads();
    {   // K frags: 4 chunks x 512 bf16 (tile = 4 KB contiguous)
        const int s = t >> 6, l = t & 63, quad = l >> 4, i16 = l & 15;
        bf16x8 o;
#pragma unroll
        for (int j = 0; j < 8; ++j) o[j] = Ktile[(s * 16 + i16) * 32 + quad * 8 + j];
        *(bf16x8*)&Kf[((size_t)(h * 64 + kt) * 4 + s) * 512 + l * 8] = o;
    }
    // V'' frags: 6 chunks x 512 bf16 (3 d-tiles x 2 key-halves; tile = 6 KB)
    for (int c = t; c < 384; c += 256) {
        const int ch = c >> 6, ll = c & 63, qd = ll >> 4, ii = ll & 15;
        const int dt = ch >> 1, kc = ch & 1;
        const int dimp = dt * 16 + ii;
        bf16x8 o;
#pragma unroll
        for (int j = 0; j < 8; ++j) {
            const int key = kc * 32 + qd * 8 + j;
            float v;
            if (dimp < 32)       v = (float)Vtile[key * 32 + dimp] * eps[key];
            else if (dimp == 32) v = eps[key];
            else                 v = 0.f;
            o[j] = (bf16)v;
        }
        *(bf16x8*)&Vf[((size_t)(h * 64 + kt) * 6 + ch) * 512 + ll * 8] = o;
    }
}

// ---------------------------------------------------------------------------
// Fixed-m flash attention, v3: block = 64 queries; each wave owns ALL 64
// queries (4 B-frags) and a 16-tile key quarter (kh = wave). K/V tile loads
// amortize over 64 queries -> half the L2 traffic of the qg-split, 4x the
// independent MFMA per iter, still zero barriers in the main loop.
// l comes from the V'' ep-row (o[2][qs] reg0 of quad 0). 4-way merge at end.
// ---------------------------------------------------------------------------
__global__ __launch_bounds__(256, 2) void attn_kernel(const bf16* __restrict__ qkvb,
                                                      const bf16* __restrict__ Kf,
                                                      const bf16* __restrict__ Vf,
                                                      bf16* __restrict__ aoh,
                                                      bf16* __restrict__ aol) {
    const int t = threadIdx.x, kh = t >> 6, lane = t & 63;
    const int quad = lane >> 4, i16 = lane & 15;
    const int qb = blockIdx.y, h = blockIdx.x;

    __shared__ __align__(16) bf16 Pt[4][4][16 * 72]; // [wave][qs][16x72]
    __shared__ __align__(16) float Mrg[3][64][48];   // kh 1..3 spill

    const int q0 = qb * 64;
    bf16x8 qf[4];
#pragma unroll
    for (int qs = 0; qs < 4; ++qs)
        qf[qs] = *(const bf16x8*)&qkvb[(size_t)(q0 + qs * 16 + i16) * 768 + h * 32 + quad * 8];

    f32x4 o[3][4];
#pragma unroll
    for (int dt = 0; dt < 3; ++dt)
#pragma unroll
        for (int qs = 0; qs < 4; ++qs) o[dt][qs] = f32x4{0.f, 0.f, 0.f, 0.f};

    const bf16* kb = Kf + (size_t)(h * 64) * 2048 + lane * 8;
    const bf16* vb = Vf + (size_t)(h * 64) * 3072 + lane * 8;

    const int kt0 = kh * 16;
    bf16x8 kcur[4];
#pragma unroll
    for (int s = 0; s < 4; ++s)
        kcur[s] = *(const bf16x8*)&kb[((size_t)kt0 * 4 + s) * 512];

    for (int it = 0; it < 16; ++it) {
        const int kt = kt0 + it;
        bf16x8 vv[6];
#pragma unroll
        for (int c = 0; c < 6; ++c)
            vv[c] = *(const bf16x8*)&vb[((size_t)kt * 6 + c) * 512];
        bf16x8 knx[4];
        if (it < 15) {
#pragma unroll
            for (int s = 0; s < 4; ++s)
                knx[s] = *(const bf16x8*)&kb[((size_t)(kt + 1) * 4 + s) * 512];
        } else {
#pragma unroll
            for (int s = 0; s < 4; ++s) knx[s] = kcur[s];
        }

        // QK^T + exp2 + P-store, two query-pairs to bound sf liveness
        const f32x4 z = {0.f, 0.f, 0.f, 0.f};
#pragma unroll
        for (int qh = 0; qh < 2; ++qh) {
            f32x4 sf[2][4];
#pragma unroll
            for (int ks = 0; ks < 4; ++ks) {
                sf[0][ks] = MFMA(kcur[ks], qf[qh * 2 + 0], z);
                sf[1][ks] = MFMA(kcur[ks], qf[qh * 2 + 1], z);
            }
#pragma unroll
            for (int qi = 0; qi < 2; ++qi) {
                const int qs = qh * 2 + qi;
#pragma unroll
                for (int ks = 0; ks < 4; ++ks) {
                    bf16x4 pk;
#pragma unroll
                    for (int r = 0; r < 4; ++r)
                        pk[r] = (bf16)__builtin_amdgcn_exp2f(sf[qi][ks][r]);
                    *(bf16x4*)&Pt[kh][qs][i16 * 72 + ks * 16 + quad * 4] = pk;
                }
            }
        }
        asm volatile("s_waitcnt lgkmcnt(0)" ::: "memory");

        // PV: O^T[dim'][query] += V''_frag x P^T  (o[2] quad0-reg0 = l)
#pragma unroll
        for (int qs = 0; qs < 4; ++qs) {
            const bf16x8 pb0 = *(const bf16x8*)&Pt[kh][qs][i16 * 72 + 0 * 32 + quad * 8];
            const bf16x8 pb1 = *(const bf16x8*)&Pt[kh][qs][i16 * 72 + 1 * 32 + quad * 8];
#pragma unroll
            for (int dt = 0; dt < 3; ++dt) {
                o[dt][qs] = MFMA(vv[dt * 2 + 0], pb0, o[dt][qs]);
                o[dt][qs] = MFMA(vv[dt * 2 + 1], pb1, o[dt][qs]);
            }
        }
#pragma unroll
        for (int s = 0; s < 4; ++s) kcur[s] = knx[s];
    }

    // 4-way kh merge (fixed m: plain sums), normalize, store hi/lo
    if (kh != 0) {
#pragma unroll
        for (int dt = 0; dt < 3; ++dt)
#pragma unroll
            for (int qs = 0; qs < 4; ++qs)
                *(f32x4*)&Mrg[kh - 1][lane][(dt * 4 + qs) * 4] = o[dt][qs];
    }
    __syncthreads();
    if (kh == 0) {
#pragma unroll
        for (int w = 0; w < 3; ++w)
#pragma unroll
            for (int dt = 0; dt < 3; ++dt)
#pragma unroll
                for (int qs = 0; qs < 4; ++qs)
                    o[dt][qs] += *(const f32x4*)&Mrg[w][lane][(dt * 4 + qs) * 4];
#pragma unroll
        for (int qs = 0; qs < 4; ++qs) {
            const float linv = 1.0f / __shfl(o[2][qs][0], i16, 64);
            const int row = q0 + qs * 16 + i16;
#pragma unroll
            for (int dt = 0; dt < 2; ++dt) {
                bf16x4 hi, lo;
#pragma unroll
                for (int r = 0; r < 4; ++r) {
                    const float v = o[dt][qs][r] * linv;
                    hi[r] = (bf16)v;
                    lo[r] = (bf16)(v - (float)hi[r]);
                }
                const size_t ob = (size_t)row * 256 + h * 32 + dt * 16 + quad * 4;
                *(bf16x4*)&aoh[ob] = hi;
                *(bf16x4*)&aol[ob] = lo;
            }
        }
    }
}

// ---------------------------------------------------------------------------
extern "C" void kernel_launch(void* const* d_in, const int* in_sizes, int n_in,
                              void* d_out, int out_size, void* d_ws, size_t ws_size,
                              hipStream_t stream) {
    const float* x    = (const float*)d_in[0];
    const float* pe   = (const float*)d_in[1];
    const float* Wqkv = (const float*)d_in[2];
    const float* bqkv = (const float*)d_in[3];
    const float* Wpe  = (const float*)d_in[4];
    const float* bpe  = (const float*)d_in[5];
    const float* Wout = (const float*)d_in[6];
    const float* bout = (const float*)d_in[7];
    float* out = (float*)d_out;

    char* ws = (char*)d_ws;
    bf16*  xh      = (bf16*)(ws);                   // 2 MB
    bf16*  xl      = (bf16*)(ws + 2097152);         // 2 MB
    bf16*  WqkvhT  = (bf16*)(ws + 4194304);         // 384 KB
    bf16*  WqkvlT  = (bf16*)(ws + 4587520);         // 384 KB
    bf16*  WouthT  = (bf16*)(ws + 4980736);         // 128 KB
    bf16*  WoutlT  = (bf16*)(ws + 5111808);         // 128 KB
    float* bqkv_s  = (float*)(ws + 5242880);        // 3 KB
    bf16*  qkvb    = (bf16*)(ws + 5245952);         // 6 MB
    float* ep      = (float*)(ws + 11537408);       // 128 KB
    bf16*  Kf      = (bf16*)(ws + 11668480);        // 2 MB
    bf16*  Vf      = (bf16*)(ws + 13765632);        // 3 MB
    bf16*  aoh     = (bf16*)(ws + 16911360);        // 2 MB
    bf16*  aol     = (bf16*)(ws + 19008512);        // 2 MB -> 21.1 MB total

    preproc_kernel<<<1217, 256, 0, stream>>>(x, Wqkv, Wout, bqkv, pe, Wpe, bpe,
                                             xh, xl, WqkvhT, WqkvlT, WouthT, WoutlT,
                                             bqkv_s, ep);
    gemm3s_kernel<768, 48, bf16><<<dim3(32, 16), 256, 0, stream>>>(xh, xl, WqkvhT, WqkvlT, bqkv_s, qkvb);
    kvtrans_kernel<<<dim3(HH, 64), 256, 0, stream>>>(qkvb, ep, Kf, Vf);
    attn_kernel<<<dim3(HH, NN / 64), 256, 0, stream>>>(qkvb, Kf, Vf, aoh, aol);
    gemm3s_kernel<256, 16, float><<<dim3(32, 16), 256, 0, stream>>>(aoh, aol, WouthT, WoutlT, bout, out);
}